// Round 5
// baseline (326.700 us; speedup 1.0000x reference)
//
#include <hip/hip_runtime.h>

#define BB 64
#define TT 512
#define HH 1024
#define CC 21
#define NROWS (BB*TT)   // 32768

// ---------------------------------------------------------------------------
// Kernel 1: emissions = hs @ W + b.
// 256 blocks x 512 threads. Block = 128 rows. Wave w: half=w>>2 (64 rows,
// lane=row), seg=w&3 (k in [seg*256, seg*256+256)).
// K-loop has NO LDS and NO barrier (R3=SMEM-serialized, R4=LDS-pipe-serialized
// at ~12cyc/ds_read_b128: both ~70us). hs streamed per-lane via depth-8
// float4 ring (full 64B lines consumed from regs -> exact 128MB HBM).
// W: 4-row windows (84 floats, 336B stride = 16B aligned) in VGPR ping-pong
// via uniform loads (L2-hot). LDS only for the final 4-segment reduce.
// ---------------------------------------------------------------------------
__global__ __launch_bounds__(512, 2) void emis_gemm(const float* __restrict__ hs,
                                                    const float* __restrict__ W,
                                                    const float* __restrict__ bias,
                                                    float* __restrict__ out) {
  __shared__ float red[4 * 128 * CC];   // segs 1..3 partials + final slab (43 KB)
  const int tid  = threadIdx.x;
  const int lane = tid & 63;
  const int w    = __builtin_amdgcn_readfirstlane(tid >> 6);
  const int half = w >> 2;
  const int seg  = w & 3;
  const int rowL = half * 64 + lane;          // 0..127
  const int row0 = blockIdx.x * 128;

  if (blockIdx.x == 0 && tid == 0) out[(size_t)NROWS * CC] = 0.f;  // loss slot

  const float4* xrow =
      reinterpret_cast<const float4*>(hs + (size_t)(row0 + rowL) * HH + seg * 256);
  const float4* Wf4 = reinterpret_cast<const float4*>(W);
  const int nw0 = seg * 64;                   // global 4-row window index base

  float4 xq[8];
#pragma unroll
  for (int i = 0; i < 8; ++i) xq[i] = xrow[i];

  float4 wb[2][21];
  {
    const float4* p = Wf4 + (size_t)nw0 * 21;
#pragma unroll
    for (int q = 0; q < 21; ++q) wb[0][q] = p[q];
  }

  float acc[CC];
#pragma unroll
  for (int c = 0; c < CC; ++c) acc[c] = 0.f;

#pragma unroll 8
  for (int kb = 0; kb < 64; ++kb) {
    const int s = kb & 7;                     // constant after unroll-8
    float4 xv = xq[s];
    int kn = kb + 8; if (kn > 63) kn = 63;    // tail: redundant reload of last line
    xq[s] = xrow[kn];
    int nw = nw0 + kb + 1; if (nw > 255) nw = 255;
    {
      const float4* p = Wf4 + (size_t)nw * 21;
      float4* dst = wb[(kb + 1) & 1];
#pragma unroll
      for (int q = 0; q < 21; ++q) dst[q] = p[q];
    }
    const float4* wc = wb[kb & 1];
#pragma unroll
    for (int r = 0; r < 4; ++r) {
      float xr = (r == 0) ? xv.x : (r == 1) ? xv.y : (r == 2) ? xv.z : xv.w;
#pragma unroll
      for (int c = 0; c < CC; ++c) {
        const int f = r * 21 + c;
        const int q = f >> 2, m = f & 3;
        float4 ww = wc[q];
        float wv = (m == 0) ? ww.x : (m == 1) ? ww.y : (m == 2) ? ww.z : ww.w;
        acc[c] = fmaf(xr, wv, acc[c]);
      }
    }
  }

  // ---- 4-segment reduction through LDS (stride 21: gcd(21,32)=1 -> <=2-way) ----
  if (seg != 0) {
#pragma unroll
    for (int c = 0; c < CC; ++c)
      red[((seg - 1) * 128 + rowL) * CC + c] = acc[c];
  }
  __syncthreads();
  if (seg == 0) {
#pragma unroll
    for (int c = 0; c < CC; ++c) {
      float v = acc[c] + bias[c];
#pragma unroll
      for (int q = 0; q < 3; ++q) v += red[(q * 128 + rowL) * CC + c];
      red[(3 * 128 + rowL) * CC + c] = v;
    }
  }
  __syncthreads();
  const float* fin = red + 3 * 128 * CC;
  for (int idx = tid; idx < 128 * CC; idx += 512)
    out[(size_t)row0 * CC + idx] = fin[idx];
}

// ---------------------------------------------------------------------------
// Kernel 2: CRF NLL — TWO-ENDED prob-space scan.
// Z = endE^T M_{n-1}...M_1 b0, M_t = diag(pm_t) E^T. Forward f <- M_t f
// (t ascending) and backward g <- M_t^T g = E (pm_t . g) (t descending) are
// independent chains; meet at mF; Z = f.g * 2^(kf+kg). Halves the serial
// dependency wall. Power-of-2 renorm per step (SALU exponent trick).
// ---------------------------------------------------------------------------
__global__ __launch_bounds__(128) void crf_kernel(const float* __restrict__ em,
                                                  const float* __restrict__ trans,
                                                  const float* __restrict__ startT,
                                                  const float* __restrict__ endT,
                                                  const int* __restrict__ att,
                                                  const int* __restrict__ labels,
                                                  float* __restrict__ loss) {
  const int b    = blockIdx.x;
  const int tid  = threadIdx.x;
  const int wave = tid >> 6;
  const int lane = tid & 63;
  __shared__ float sh_num;
  __shared__ int   sh_len;

  const float L2E = 1.4426950408889634f;
  const float LN2 = 0.6931471805599453f;

  if (wave == 1) {
    int cnt = 0;
    for (int t = lane; t < TT; t += 64) {
      bool m = (t == 0) || ((att[b * TT + t] != 0) && (labels[b * TT + t] != -100));
      cnt += m ? 1 : 0;
    }
#pragma unroll
    for (int off = 32; off >= 1; off >>= 1) cnt += __shfl_down(cnt, off);
    cnt = __shfl(cnt, 0);

    float s = 0.f;
    for (int t = lane + 1; t < TT; t += 64) {
      bool m = (att[b * TT + t] != 0) && (labels[b * TT + t] != -100);
      if (m) {
        int tp = labels[b * TT + t - 1], tc = labels[b * TT + t];
        s += trans[tp * CC + tc] + em[((size_t)b * TT + t) * CC + tc];
      }
    }
#pragma unroll
    for (int off = 32; off >= 1; off >>= 1) s += __shfl_down(s, off);
    if (lane == 0) {
      int tag0 = labels[b * TT];
      int lastTag = labels[b * TT + cnt - 1];
      s += startT[tag0] + em[((size_t)b * TT) * CC + tag0] + endT[lastTag];
      sh_num = s;
      sh_len = cnt;
    }
  }

  const int j = lane < CC ? lane : CC - 1;
  float E[CC], F[CC];
  float f = 0.f, g = 0.f;
  if (wave == 0) {
#pragma unroll
    for (int i = 0; i < CC; ++i) {
      E[i] = __builtin_amdgcn_exp2f(trans[i * CC + j] * L2E);  // column j
      F[i] = __builtin_amdgcn_exp2f(trans[j * CC + i] * L2E);  // row j
    }
    f = __builtin_amdgcn_exp2f((startT[j] + em[((size_t)b * TT) * CC + j]) * L2E);
    g = __builtin_amdgcn_exp2f(endT[j] * L2E);
  }
  __syncthreads();
  if (wave != 0) return;

  const int len = sh_len;
  const int L  = len - 1;
  const int mF = (L + 1) >> 1;      // forward steps: t = 1..mF
  const int mB = L - mF;            // backward steps: t = len-1 .. mF+1
  int kf = 0, kg = 0;

  float sf[CC];
#pragma unroll
  for (int i = 0; i < CC; ++i)
    sf[i] = __int_as_float(__builtin_amdgcn_readlane(__float_as_int(f), i));

  const float* emB = em + (size_t)b * TT * CC;

  // depth-4 prefetch rings, both directions (memory-safe clamps; TT=512)
  float rf[4], rb[4];
#pragma unroll
  for (int u = 0; u < 4; ++u) {
    int tf = 1 + u; if (tf > TT - 1) tf = TT - 1;
    rf[u] = emB[(size_t)tf * CC + j];
    int tb = len - 1 - u; if (tb < 0) tb = 0;
    rb[u] = emB[(size_t)tb * CC + j];
  }

  int it = 0;
  while (it < mF) {
#pragma unroll
    for (int u = 0; u < 4; ++u) {
      const int i2 = it + u;
      if (i2 < mF) {                 // ---- forward step, t = 1+i2 ----
        float pm = __builtin_amdgcn_exp2f(rf[u] * L2E);
        int tp = 1 + i2 + 4; if (tp > TT - 1) tp = TT - 1;
        rf[u] = emB[(size_t)tp * CC + j];
        int ef = (__float_as_int(sf[0]) >> 23) & 255;
        kf += ef - 127;
        float pms = pm * __int_as_float((254 - ef) << 23);
        float c0 = 0.f, c1 = 0.f, c2 = 0.f;
#pragma unroll
        for (int i = 0; i < CC; i += 3) c0 = fmaf(sf[i], E[i], c0);
#pragma unroll
        for (int i = 1; i < CC; i += 3) c1 = fmaf(sf[i], E[i], c1);
#pragma unroll
        for (int i = 2; i < CC; i += 3) c2 = fmaf(sf[i], E[i], c2);
        f = ((c0 + c1) + c2) * pms;
#pragma unroll
        for (int i = 0; i < CC; ++i)
          sf[i] = __int_as_float(__builtin_amdgcn_readlane(__float_as_int(f), i));
      }
      if (i2 < mB) {                 // ---- backward step, t = len-1-i2 ----
        float pm = __builtin_amdgcn_exp2f(rb[u] * L2E);
        int tb = len - 1 - i2 - 4; if (tb < 0) tb = 0;
        rb[u] = emB[(size_t)tb * CC + j];
        float h = pm * g;
        float sh_[CC];
#pragma unroll
        for (int i = 0; i < CC; ++i)
          sh_[i] = __int_as_float(__builtin_amdgcn_readlane(__float_as_int(h), i));
        int eg = (__float_as_int(sh_[0]) >> 23) & 255;
        kg += eg - 127;
        float sB = __int_as_float((254 - eg) << 23);
        float d0 = 0.f, d1 = 0.f, d2 = 0.f;
#pragma unroll
        for (int i = 0; i < CC; i += 3) d0 = fmaf(sh_[i], F[i], d0);
#pragma unroll
        for (int i = 1; i < CC; i += 3) d1 = fmaf(sh_[i], F[i], d1);
#pragma unroll
        for (int i = 2; i < CC; i += 3) d2 = fmaf(sh_[i], F[i], d2);
        g = ((d0 + d1) + d2) * sB;
      }
    }
    it += 4;
  }

  // Z = sum_j f_j g_j * 2^(kf+kg)
  float v = (lane < CC) ? f * g : 0.f;
#pragma unroll
  for (int off = 32; off >= 1; off >>= 1) v += __shfl_xor(v, off);
  if (lane == 0) {
    float logZ = (float)(kf + kg) * LN2 + LN2 * __builtin_amdgcn_logf(v);
    atomicAdd(loss, -(sh_num - logZ) * (1.0f / 64.0f));
  }
}

extern "C" void kernel_launch(void* const* d_in, const int* in_sizes, int n_in,
                              void* d_out, int out_size, void* d_ws, size_t ws_size,
                              hipStream_t stream) {
  const float* hs     = (const float*)d_in[0];
  const float* W      = (const float*)d_in[1];
  const float* bias   = (const float*)d_in[2];
  const float* trans  = (const float*)d_in[3];
  const float* startT = (const float*)d_in[4];
  const float* endT   = (const float*)d_in[5];
  const int*   att    = (const int*)d_in[6];
  const int*   labels = (const int*)d_in[7];
  float* out = (float*)d_out;

  emis_gemm<<<dim3(256), dim3(512), 0, stream>>>(hs, W, bias, out);
  crf_kernel<<<dim3(64), dim3(128), 0, stream>>>(out, trans, startT, endT, att,
                                                 labels, out + (size_t)NROWS * CC);
}

// Round 6
// 289.222 us; speedup vs baseline: 1.1296x; 1.1296x over previous
//
#include <hip/hip_runtime.h>

#define BB 64
#define TT 512
#define HH 1024
#define CC 21
#define NROWS (BB*TT)   // 32768

typedef __attribute__((ext_vector_type(8)))  short  short8;   // 8 bf16 (4 VGPR)
typedef __attribute__((ext_vector_type(16))) float  float16;  // MFMA 32x32 acc

// ---------------------------------------------------------------------------
// Kernel 0: split W (1024x21 fp32) into bf16 hi/lo, padded to [32][1024]
// (n-major) in d_ws. hi = truncate-top-16; lo = bf16(v - hi) -> v is
// represented to ~2^-17 relative; the dropped lo*lo MFMA term is ~2^-18.
// ---------------------------------------------------------------------------
__global__ __launch_bounds__(256) void wprep(const float* __restrict__ W,
                                             unsigned short* __restrict__ wpad) {
  int idx = blockIdx.x * 256 + threadIdx.x;      // 32768 = 32 n * 1024 k
  int n = idx >> 10, k = idx & 1023;
  float v = (n < CC) ? W[k * CC + n] : 0.f;
  unsigned b = __float_as_uint(v);
  float lo = v - __uint_as_float(b & 0xFFFF0000u);
  wpad[idx]         = (unsigned short)(b >> 16);
  wpad[32768 + idx] = (unsigned short)(__float_as_uint(lo) >> 16);
}

// ---------------------------------------------------------------------------
// Kernel 1: emissions = hs @ W + b via split-bf16 MFMA.
// 1024 blocks x 64 threads (1 wave = one 32-row tile, full K=1024).
// R3/R4/R5 all serialized on the pipe delivering 21 W values per k
// (SMEM/LDS/VMEM ~ 70-108us). MFMA delivers a 16x32x16 fp32-accurate
// product per 3 instructions with operands at 1KB/instr from VGPRs.
// A: per-lane depth-8 float4 ring from global (no LDS/barrier; exact-read
// 128MB). B: depth-4 short8 ring from L2-hot wpad. 3 MFMA/k-step
// (hi*hi + hi*lo + lo*hi).
// A frag: A[m=lane&31][k=(lane>>5)*8+j]; B frag: B[k=(lane>>5)*8+j][n=lane&31];
// C/D: col=lane&31, row=(reg&3)+8*(reg>>2)+4*(lane>>5)  [m74/m101-verified].
// ---------------------------------------------------------------------------
__global__ __launch_bounds__(64) void emis_mfma(const float* __restrict__ hs,
                                                const unsigned short* __restrict__ wpad,
                                                const float* __restrict__ bias,
                                                float* __restrict__ out) {
  const int lane = threadIdx.x;
  const int m    = lane & 31;
  const int half = lane >> 5;
  const int row0 = blockIdx.x * 32;

  if (blockIdx.x == 0 && lane == 0) out[(size_t)NROWS * CC] = 0.f;  // loss slot

  const float4* arow =
      reinterpret_cast<const float4*>(hs + (size_t)(row0 + m) * HH) + half * 2;
  const unsigned short* whi = wpad + m * 1024 + half * 8;
  const unsigned short* wlo = whi + 32768;

  float16 acc;
#pragma unroll
  for (int i = 0; i < 16; ++i) acc[i] = 0.f;

  float4 xa[8], xb[8];
#pragma unroll
  for (int i = 0; i < 8; ++i) { xa[i] = arow[i * 4]; xb[i] = arow[i * 4 + 1]; }
  short8 bhq[4], blq[4];
#pragma unroll
  for (int i = 0; i < 4; ++i) {
    bhq[i] = *reinterpret_cast<const short8*>(whi + i * 16);
    blq[i] = *reinterpret_cast<const short8*>(wlo + i * 16);
  }

#pragma unroll 8
  for (int kb = 0; kb < 64; ++kb) {
    const int s8 = kb & 7, s4 = kb & 3;
    float4 a0 = xa[s8], a1 = xb[s8];
    int kn = kb + 8; if (kn > 63) kn = 63;          // tail: redundant reload
    xa[s8] = arow[kn * 4];
    xb[s8] = arow[kn * 4 + 1];
    short8 bh = bhq[s4], bl = blq[s4];
    int kw = kb + 4; if (kw > 63) kw = 63;
    bhq[s4] = *reinterpret_cast<const short8*>(whi + kw * 16);
    blq[s4] = *reinterpret_cast<const short8*>(wlo + kw * 16);

    float af[8] = {a0.x, a0.y, a0.z, a0.w, a1.x, a1.y, a1.z, a1.w};
    short8 ah, al;
#pragma unroll
    for (int j = 0; j < 8; ++j) {
      unsigned b = __float_as_uint(af[j]);
      ah[j] = (short)(b >> 16);
      float lo = af[j] - __uint_as_float(b & 0xFFFF0000u);
      al[j] = (short)(__float_as_uint(lo) >> 16);
    }
    acc = __builtin_amdgcn_mfma_f32_32x32x16_bf16(ah, bh, acc, 0, 0, 0);
    acc = __builtin_amdgcn_mfma_f32_32x32x16_bf16(ah, bl, acc, 0, 0, 0);
    acc = __builtin_amdgcn_mfma_f32_32x32x16_bf16(al, bh, acc, 0, 0, 0);
  }

  float bv = (m < CC) ? bias[m] : 0.f;
#pragma unroll
  for (int r = 0; r < 16; ++r) {
    int row = (r & 3) + 8 * (r >> 2) + 4 * half;
    if (m < CC) out[(size_t)(row0 + row) * CC + m] = acc[r] + bv;
  }
}

// ---------------------------------------------------------------------------
// Kernel 2: CRF NLL — unchanged from R5 (two-ended prob-space scan);
// isolating the GEMM change this round.
// ---------------------------------------------------------------------------
__global__ __launch_bounds__(128) void crf_kernel(const float* __restrict__ em,
                                                  const float* __restrict__ trans,
                                                  const float* __restrict__ startT,
                                                  const float* __restrict__ endT,
                                                  const int* __restrict__ att,
                                                  const int* __restrict__ labels,
                                                  float* __restrict__ loss) {
  const int b    = blockIdx.x;
  const int tid  = threadIdx.x;
  const int wave = tid >> 6;
  const int lane = tid & 63;
  __shared__ float sh_num;
  __shared__ int   sh_len;

  const float L2E = 1.4426950408889634f;
  const float LN2 = 0.6931471805599453f;

  if (wave == 1) {
    int cnt = 0;
    for (int t = lane; t < TT; t += 64) {
      bool m = (t == 0) || ((att[b * TT + t] != 0) && (labels[b * TT + t] != -100));
      cnt += m ? 1 : 0;
    }
#pragma unroll
    for (int off = 32; off >= 1; off >>= 1) cnt += __shfl_down(cnt, off);
    cnt = __shfl(cnt, 0);

    float s = 0.f;
    for (int t = lane + 1; t < TT; t += 64) {
      bool m = (att[b * TT + t] != 0) && (labels[b * TT + t] != -100);
      if (m) {
        int tp = labels[b * TT + t - 1], tc = labels[b * TT + t];
        s += trans[tp * CC + tc] + em[((size_t)b * TT + t) * CC + tc];
      }
    }
#pragma unroll
    for (int off = 32; off >= 1; off >>= 1) s += __shfl_down(s, off);
    if (lane == 0) {
      int tag0 = labels[b * TT];
      int lastTag = labels[b * TT + cnt - 1];
      s += startT[tag0] + em[((size_t)b * TT) * CC + tag0] + endT[lastTag];
      sh_num = s;
      sh_len = cnt;
    }
  }

  const int j = lane < CC ? lane : CC - 1;
  float E[CC], F[CC];
  float f = 0.f, g = 0.f;
  if (wave == 0) {
#pragma unroll
    for (int i = 0; i < CC; ++i) {
      E[i] = __builtin_amdgcn_exp2f(trans[i * CC + j] * L2E);  // column j
      F[i] = __builtin_amdgcn_exp2f(trans[j * CC + i] * L2E);  // row j
    }
    f = __builtin_amdgcn_exp2f((startT[j] + em[((size_t)b * TT) * CC + j]) * L2E);
    g = __builtin_amdgcn_exp2f(endT[j] * L2E);
  }
  __syncthreads();
  if (wave != 0) return;

  const int len = sh_len;
  const int L  = len - 1;
  const int mF = (L + 1) >> 1;
  const int mB = L - mF;
  int kf = 0, kg = 0;

  float sf[CC];
#pragma unroll
  for (int i = 0; i < CC; ++i)
    sf[i] = __int_as_float(__builtin_amdgcn_readlane(__float_as_int(f), i));

  const float* emB = em + (size_t)b * TT * CC;

  float rf[4], rb[4];
#pragma unroll
  for (int u = 0; u < 4; ++u) {
    int tf = 1 + u; if (tf > TT - 1) tf = TT - 1;
    rf[u] = emB[(size_t)tf * CC + j];
    int tb = len - 1 - u; if (tb < 0) tb = 0;
    rb[u] = emB[(size_t)tb * CC + j];
  }

  int it = 0;
  while (it < mF) {
#pragma unroll
    for (int u = 0; u < 4; ++u) {
      const int i2 = it + u;
      if (i2 < mF) {                 // forward step, t = 1+i2
        float pm = __builtin_amdgcn_exp2f(rf[u] * L2E);
        int tp = 1 + i2 + 4; if (tp > TT - 1) tp = TT - 1;
        rf[u] = emB[(size_t)tp * CC + j];
        int ef = (__float_as_int(sf[0]) >> 23) & 255;
        kf += ef - 127;
        float pms = pm * __int_as_float((254 - ef) << 23);
        float c0 = 0.f, c1 = 0.f, c2 = 0.f;
#pragma unroll
        for (int i = 0; i < CC; i += 3) c0 = fmaf(sf[i], E[i], c0);
#pragma unroll
        for (int i = 1; i < CC; i += 3) c1 = fmaf(sf[i], E[i], c1);
#pragma unroll
        for (int i = 2; i < CC; i += 3) c2 = fmaf(sf[i], E[i], c2);
        f = ((c0 + c1) + c2) * pms;
#pragma unroll
        for (int i = 0; i < CC; ++i)
          sf[i] = __int_as_float(__builtin_amdgcn_readlane(__float_as_int(f), i));
      }
      if (i2 < mB) {                 // backward step, t = len-1-i2
        float pm = __builtin_amdgcn_exp2f(rb[u] * L2E);
        int tb = len - 1 - i2 - 4; if (tb < 0) tb = 0;
        rb[u] = emB[(size_t)tb * CC + j];
        float h = pm * g;
        float sh_[CC];
#pragma unroll
        for (int i = 0; i < CC; ++i)
          sh_[i] = __int_as_float(__builtin_amdgcn_readlane(__float_as_int(h), i));
        int eg = (__float_as_int(sh_[0]) >> 23) & 255;
        kg += eg - 127;
        float sB = __int_as_float((254 - eg) << 23);
        float d0 = 0.f, d1 = 0.f, d2 = 0.f;
#pragma unroll
        for (int i = 0; i < CC; i += 3) d0 = fmaf(sh_[i], F[i], d0);
#pragma unroll
        for (int i = 1; i < CC; i += 3) d1 = fmaf(sh_[i], F[i], d1);
#pragma unroll
        for (int i = 2; i < CC; i += 3) d2 = fmaf(sh_[i], F[i], d2);
        g = ((d0 + d1) + d2) * sB;
      }
    }
    it += 4;
  }

  float v = (lane < CC) ? f * g : 0.f;
#pragma unroll
  for (int off = 32; off >= 1; off >>= 1) v += __shfl_xor(v, off);
  if (lane == 0) {
    float logZ = (float)(kf + kg) * LN2 + LN2 * __builtin_amdgcn_logf(v);
    atomicAdd(loss, -(sh_num - logZ) * (1.0f / 64.0f));
  }
}

extern "C" void kernel_launch(void* const* d_in, const int* in_sizes, int n_in,
                              void* d_out, int out_size, void* d_ws, size_t ws_size,
                              hipStream_t stream) {
  const float* hs     = (const float*)d_in[0];
  const float* W      = (const float*)d_in[1];
  const float* bias   = (const float*)d_in[2];
  const float* trans  = (const float*)d_in[3];
  const float* startT = (const float*)d_in[4];
  const float* endT   = (const float*)d_in[5];
  const int*   att    = (const int*)d_in[6];
  const int*   labels = (const int*)d_in[7];
  float* out = (float*)d_out;
  unsigned short* wpad = (unsigned short*)d_ws;   // 128 KB

  wprep<<<dim3(128), dim3(256), 0, stream>>>(W, wpad);
  emis_mfma<<<dim3(1024), dim3(64), 0, stream>>>(hs, wpad, bias, out);
  crf_kernel<<<dim3(64), dim3(128), 0, stream>>>(out, trans, startT, endT, att,
                                                 labels, out + (size_t)NROWS * CC);
}